// Round 1
// 188.303 us; speedup vs baseline: 1.1338x; 1.1338x over previous
//
#include <hip/hip_runtime.h>

// ---------------------------------------------------------------------------
// CirculantLinear, fully fused GEMM path.
//
// Karatsuba in frequency space: K1=(Xr+Xi)Er, K2=Xr(Ei-Er), K3=Xi(Ei+Er)
//   Or = K1-K3, Oi = K1+K2
// Key restructure vs v2: ONE flat K=5120 bf16 GEMM per output tile.
//   A  = Xp 4096 x 5120 = [Xs | Xr | Xi | X0 | X2]
//   B  = Bp 1024 x 5120 = [Er | Ei-Er | -(Ei+Er) | E0 | E2]   (row = y)
// Accumulator target switches every 1024 k:
//   aK1 (k 0..1023) -> copy to aOi -> aOi += K2 -> aK1 += (-K3) = Or
//   -> aO0 -> aO2.  Length-4 irfft applied in the epilogue; writes final
// output only (64 MiB).  post_k and the K3 buffer are eliminated.
//
// gemm_f: 512 thr (8 waves, 2x4), 128x128 compressed tile (=128x512 out),
// BK=64, 2-phase double-buffered global_load_lds prefetch, XOR-swizzled LDS
// (both-sides: permuted global source + swizzled ds_read), XCD-aware grid.
//
// ws: [0,40MiB) Xp bf16 4096x5120 ; [40,50MiB) Bp bf16 1024x5120
// ---------------------------------------------------------------------------

typedef __attribute__((ext_vector_type(8))) short bf16x8_t;
typedef __attribute__((ext_vector_type(4))) float f32x4_t;

#define NDIM 4096
#define TILE 128
#define BK 32

__device__ __forceinline__ unsigned short f2bf(float f) {
    unsigned int u = __builtin_bit_cast(unsigned int, f);
    u += 0x7fffu + ((u >> 16) & 1u);
    return (unsigned short)(u >> 16);
}

__device__ __forceinline__ void async_copy16(const void* g, void* l) {
    __builtin_amdgcn_global_load_lds(
        (const __attribute__((address_space(1))) void*)g,
        (__attribute__((address_space(3))) void*)l,
        16, 0, 0);
}

// ======================= PRIMARY (fused) path ==============================

// pre-pass: 4 mini-blocks per thread, 8-byte stores per panel.
// blocks [0,4096): x -> Xp [Xs|Xr|Xi|X0|X2]
// blocks [4096,5120): eigens -> Bp [Er|Ei-Er|-(Ei+Er)|E0|E2]
__global__ __launch_bounds__(256) void pre_k(const float* __restrict__ x,
                                             const float* __restrict__ eig,
                                             unsigned short* __restrict__ xp,
                                             unsigned short* __restrict__ B) {
    const int t = threadIdx.x;
    if (blockIdx.x < 4096) {
        int gid = blockIdx.x * 256 + t;
        int b = gid >> 8, j0 = (gid & 255) << 2;
        const float4* src = (const float4*)x + ((size_t)b << 10) + j0;
        unsigned short S[4], R[4], Mi[4], Z[4], T[4];
#pragma unroll
        for (int q = 0; q < 4; ++q) {
            float4 v = src[q];
            float r = v.x - v.z, m = v.w - v.y;
            S[q]  = f2bf(r + m);                     // Xs = Xr+Xi
            R[q]  = f2bf(r);                         // Xr
            Mi[q] = f2bf(m);                         // Xi
            Z[q]  = f2bf(v.x + v.y + v.z + v.w);     // X0
            T[q]  = f2bf(v.x - v.y + v.z - v.w);     // X2
        }
        unsigned short* dst = xp + (size_t)b * 5120 + j0;
        *(ushort4*)(dst)        = *(const ushort4*)S;
        *(ushort4*)(dst + 1024) = *(const ushort4*)R;
        *(ushort4*)(dst + 2048) = *(const ushort4*)Mi;
        *(ushort4*)(dst + 3072) = *(const ushort4*)Z;
        *(ushort4*)(dst + 4096) = *(const ushort4*)T;
    } else {
        int gid = (blockIdx.x - 4096) * 256 + t;
        int y = gid >> 8, c0 = (gid & 255) << 2;
        const float4* src = (const float4*)eig + ((size_t)y << 10) + c0;
        unsigned short P0[4], P1[4], P2[4], P3[4], P4[4];
#pragma unroll
        for (int q = 0; q < 4; ++q) {
            float4 v = src[q];
            float r = v.x - v.z, m = v.w - v.y;      // Er, Ei
            P0[q] = f2bf(r);                         // Er
            P1[q] = f2bf(m - r);                     // Ei-Er
            P2[q] = f2bf(-(m + r));                  // -(Ei+Er)
            P3[q] = f2bf(v.x + v.y + v.z + v.w);     // E0
            P4[q] = f2bf(v.x - v.y + v.z - v.w);     // E2
        }
        unsigned short* dst = B + (size_t)y * 5120 + c0;
        *(ushort4*)(dst)        = *(const ushort4*)P0;
        *(ushort4*)(dst + 1024) = *(const ushort4*)P1;
        *(ushort4*)(dst + 2048) = *(const ushort4*)P2;
        *(ushort4*)(dst + 3072) = *(const ushort4*)P3;
        *(ushort4*)(dst + 4096) = *(const ushort4*)P4;
    }
}

// Fused GEMM + irfft epilogue.
// Grid: 256 blocks = 32 rowBlks x 8 colBlks, 1 block/CU.
__global__ __launch_bounds__(512, 2) void gemm_f(
        const unsigned short* __restrict__ A,   // Xp 4096 x 5120
        const unsigned short* __restrict__ B,   // Bp 1024 x 5120
        float* __restrict__ C) {                // out 4096 x 4096
    // [buf][ A tile 128x64 u16 (16KB) | B tile 128x64 u16 (16KB) ]
    __shared__ unsigned short sm[2][16384];

    // XCD swizzle: xcd k gets rowBlks 4k..4k+3, all 8 colBlks (A-slab reuse in L2)
    const int raw    = blockIdx.x;
    const int xcd    = raw & 7;
    const int idx    = raw >> 3;                 // [0,32)
    const int rowBlk = xcd * 4 + (idx >> 3);     // [0,32)
    const int colBlk = idx & 7;                  // [0,8)

    const int t    = threadIdx.x;
    const int lane = t & 63;
    const int w    = t >> 6;                     // [0,8)
    const int wm   = (w >> 2) * 64;              // 2 M-waves
    const int wn   = (w & 3) * 32;               // 4 N-waves
    const int lr   = lane & 15;
    const int quad = lane >> 4;
    const int xr   = lr & 7;                     // read-side XOR swizzle key

    // staging: thread t loads 16B for LDS slot (row=t>>3, col8=t&7); the
    // GLOBAL source is pre-swizzled (col8L = col8 ^ (row&7)) so swizzled
    // reads below see logical data (rule: both-sides-or-neither).
    const int srow = t >> 3;                                   // [0,64)
    const int scol = ((t & 7) ^ ((t >> 3) & 7)) << 3;          // u16 in BK=64 window
    const unsigned short* pa0 = A + (size_t)(rowBlk * 128 + srow) * 5120 + scol;
    const unsigned short* pa1 = pa0 + (size_t)64 * 5120;
    const unsigned short* pb0 = B + (size_t)(colBlk * 128 + srow) * 5120 + scol;
    const unsigned short* pb1 = pb0 + (size_t)64 * 5120;

    char* smb  = (char*)&sm[0][0];
    char* dstT = smb + (size_t)t * 16;

    int koff = 0;   // next k (u16) to prefetch
    int cur  = 0;

    f32x4_t aK1[4][2] = {};   // K1, becomes Or
    f32x4_t aOi[4][2];        // Oi = K1 + K2 (init by copy)
    f32x4_t aO0[4][2] = {};
    f32x4_t aO2[4][2] = {};

#define STAGE_F(BUF)                                           \
    {                                                          \
        char* d = dstT + (BUF) * 32768;                        \
        async_copy16(pa0 + koff, d);                           \
        async_copy16(pa1 + koff, d + 8192);                    \
        async_copy16(pb0 + koff, d + 16384);                   \
        async_copy16(pb1 + koff, d + 24576);                   \
        koff += 64;                                            \
    }

#define COMPUTE_F(BUF, ACC)                                                   \
    {                                                                         \
        const char* ab = smb + (BUF) * 32768 + (wm + lr) * 128;               \
        const char* bb = smb + (BUF) * 32768 + 16384 + (wn + lr) * 128;       \
        _Pragma("unroll")                                                     \
        for (int kk = 0; kk < 2; ++kk) {                                      \
            const int sw = ((((kk << 2) | quad)) ^ xr) << 4;                  \
            bf16x8_t af[4], bfv[2];                                           \
            _Pragma("unroll")                                                 \
            for (int i = 0; i < 4; ++i)                                       \
                af[i] = *(const bf16x8_t*)(ab + i * 2048 + sw);               \
            _Pragma("unroll")                                                 \
            for (int j = 0; j < 2; ++j)                                       \
                bfv[j] = *(const bf16x8_t*)(bb + j * 2048 + sw);              \
            _Pragma("unroll")                                                 \
            for (int mt = 0; mt < 4; ++mt)                                    \
                _Pragma("unroll")                                             \
                for (int nt = 0; nt < 2; ++nt)                                \
                    ACC[mt][nt] = __builtin_amdgcn_mfma_f32_16x16x32_bf16(    \
                        af[mt], bfv[nt], ACC[mt][nt], 0, 0, 0);               \
        }                                                                     \
    }

    // 2-phase pipeline: STAGE(next) issued BEFORE compute(cur); one
    // vmcnt(0)+barrier per step (T3 minimum recipe).
#define PHASE_F(ACC, ISLAST)                                   \
    _Pragma("unroll 2")                                        \
    for (int s2 = 0; s2 < 16; ++s2) {                          \
        if (!(ISLAST) || s2 < 15) STAGE_F(cur ^ 1);            \
        COMPUTE_F(cur, ACC);                                   \
        asm volatile("s_waitcnt vmcnt(0)" ::: "memory");       \
        __syncthreads();                                       \
        cur ^= 1;                                              \
    }

    // prologue
    STAGE_F(0);
    asm volatile("s_waitcnt vmcnt(0)" ::: "memory");
    __syncthreads();

    PHASE_F(aK1, 0)                 // k [   0,1024): K1 = Xs*Er
#pragma unroll
    for (int mt = 0; mt < 4; ++mt)
#pragma unroll
        for (int nt = 0; nt < 2; ++nt) aOi[mt][nt] = aK1[mt][nt];
    PHASE_F(aOi, 0)                 // k [1024,2048): += K2  -> Oi
    PHASE_F(aK1, 0)                 // k [2048,3072): += -K3 -> Or
    PHASE_F(aO0, 0)                 // k [3072,4096): O0
    PHASE_F(aO2, 1)                 // k [4096,5120): O2

#undef PHASE_F
#undef COMPUTE_F
#undef STAGE_F

    // epilogue: irfft4 in registers, final-output float4 stores only.
    const int orow0 = rowBlk * 128 + wm + quad * 4;
    const int yc0   = colBlk * 128 + wn + lr;
#pragma unroll
    for (int mt = 0; mt < 4; ++mt) {
#pragma unroll
        for (int r = 0; r < 4; ++r) {
            float* dst = C + (size_t)(orow0 + mt * 16 + r) * NDIM;
#pragma unroll
            for (int nt = 0; nt < 2; ++nt) {
                int yc = yc0 + nt * 16;
                float O0 = aO0[mt][nt][r], Or = aK1[mt][nt][r];
                float Oi = aOi[mt][nt][r], O2 = aO2[mt][nt][r];
                float4 o;
                o.x = 0.25f * (O0 + 2.0f * Or + O2);
                o.y = 0.25f * (O0 - 2.0f * Oi - O2);
                o.z = 0.25f * (O0 - 2.0f * Or + O2);
                o.w = 0.25f * (O0 + 2.0f * Oi - O2);
                *(float4*)(dst + 4 * yc) = o;
            }
        }
    }
}

// ======================= FALLBACK (round-2 path) ===========================

__global__ __launch_bounds__(256) void fwd_x_fb(const float* __restrict__ x,
                                                unsigned short* __restrict__ xp) {
    int gid = blockIdx.x * 256 + threadIdx.x;
    int b = gid >> 10, j = gid & 1023;
    float4 v = ((const float4*)x)[(size_t)b * 1024 + j];
    unsigned short* dst = xp + (size_t)b * NDIM + j;
    dst[0]    = f2bf(v.x + v.y + v.z + v.w);
    dst[1024] = f2bf(v.x - v.z);
    dst[2048] = f2bf(v.w - v.y);
    dst[3072] = f2bf(v.x - v.y + v.z - v.w);
}

__global__ __launch_bounds__(256) void build_b_fb(const float* __restrict__ eig,
                                                  unsigned short* __restrict__ B) {
    int gid = blockIdx.x * 256 + threadIdx.x;
    int y = gid >> 10, c = gid & 1023;
    float4 v = ((const float4*)eig)[(size_t)y * 1024 + c];
    float r = v.x - v.z, s = v.w - v.y;
    B[(size_t)y * 1024 + c] = f2bf(v.x + v.y + v.z + v.w);
    unsigned short* b1r = B + 1048576 + (size_t)y * 2048;
    b1r[c]        = f2bf(r);
    b1r[1024 + c] = f2bf(-s);
    unsigned short* b1i = B + 3145728 + (size_t)y * 2048;
    b1i[c]        = f2bf(s);
    b1i[1024 + c] = f2bf(r);
    B[5242880 + (size_t)y * 1024 + c] = f2bf(v.x - v.y + v.z - v.w);
}

__global__ __launch_bounds__(256, 2) void gemm_fb(
        const unsigned short* __restrict__ A,
        const unsigned short* __restrict__ B,
        float* __restrict__ C) {
    __shared__ unsigned short lA[TILE * BK];
    __shared__ unsigned short lB[TILE * BK];

    const int Ks[4]   = {1024, 2048, 2048, 1024};
    const int Aoff[4] = {0, 1024, 1024, 3072};
    const size_t Boff[4] = {0u, 1048576u, 3145728u, 5242880u};

    int lin = blockIdx.x;
    int seg, nseg, blkM;
    if (lin < 512) { seg = 1 + ((lin >> 3) & 1); nseg = lin & 7; blkM = lin >> 4; }
    else { int i = lin - 512; seg = ((i >> 3) & 1) * 3; nseg = i & 7; blkM = i >> 4; }

    const int K    = Ks[seg];
    const int aoff = Aoff[seg];
    const unsigned short* Bs = B + Boff[seg];

    const int t    = threadIdx.x;
    const int lane = t & 63;
    const int w    = t >> 6;
    const int wm   = (w >> 1) * 64;
    const int wn   = (w & 1) * 64;
    const int lr   = lane & 15;
    const int quad = lane >> 4;

    const int e0 = t * 8;
    const int r0 = e0 >> 5;
    const int c0 = e0 & 31;

    const unsigned short* pa0 = A + (size_t)(blkM * TILE + r0) * NDIM + aoff + c0;
    const unsigned short* pa1 = pa0 + (size_t)64 * NDIM;
    const unsigned short* pb0 = Bs + (size_t)(nseg * TILE + r0) * K + c0;
    const unsigned short* pb1 = pb0 + (size_t)64 * K;

    unsigned short* dA0 = &lA[e0];
    unsigned short* dA1 = &lA[2048 + e0];
    unsigned short* dB0 = &lB[e0];
    unsigned short* dB1 = &lB[2048 + e0];

    const unsigned short* la0 = &lA[(wm + lr) * BK + quad * 8];
    const unsigned short* lb0 = &lB[(wn + lr) * BK + quad * 8];

    f32x4_t acc[4][4] = {};

    for (int k0 = 0; k0 < K; k0 += BK) {
        async_copy16(pa0 + k0, dA0);
        async_copy16(pa1 + k0, dA1);
        async_copy16(pb0 + k0, dB0);
        async_copy16(pb1 + k0, dB1);
        asm volatile("s_waitcnt vmcnt(0)" ::: "memory");
        __syncthreads();

        bf16x8_t af[4], bfr[4];
#pragma unroll
        for (int i = 0; i < 4; ++i)
            af[i] = *(const bf16x8_t*)(la0 + i * 16 * BK);
#pragma unroll
        for (int i = 0; i < 4; ++i)
            bfr[i] = *(const bf16x8_t*)(lb0 + i * 16 * BK);

#pragma unroll
        for (int mt = 0; mt < 4; ++mt)
#pragma unroll
            for (int nt = 0; nt < 4; ++nt)
                acc[mt][nt] = __builtin_amdgcn_mfma_f32_16x16x32_bf16(
                    af[mt], bfr[nt], acc[mt][nt], 0, 0, 0);

        __syncthreads();
    }

    const int orow0 = blkM * TILE + wm + quad * 4;
    const int ocol0 = seg * 1024 + nseg * TILE + wn + lr;
#pragma unroll
    for (int mt = 0; mt < 4; ++mt) {
#pragma unroll
        for (int r = 0; r < 4; ++r) {
            float* dst = C + (size_t)(orow0 + mt * 16 + r) * NDIM + ocol0;
#pragma unroll
            for (int nt = 0; nt < 4; ++nt)
                dst[nt * 16] = acc[mt][nt][r];
        }
    }
}

__global__ __launch_bounds__(256) void post_fb(float* __restrict__ O) {
    float* row = O + (size_t)blockIdx.x * NDIM;
    const int t = threadIdx.x;
    float4 v0 = *(const float4*)(row + 4 * t);
    float4 vr = *(const float4*)(row + 1024 + 4 * t);
    float4 vi = *(const float4*)(row + 2048 + 4 * t);
    float4 v2 = *(const float4*)(row + 3072 + 4 * t);
    __syncthreads();
    const float* a0 = (const float*)&v0;
    const float* ar = (const float*)&vr;
    const float* ai = (const float*)&vi;
    const float* a2 = (const float*)&v2;
#pragma unroll
    for (int i = 0; i < 4; ++i) {
        float4 o;
        o.x = 0.25f * (a0[i] + 2.0f * ar[i] + a2[i]);
        o.y = 0.25f * (a0[i] - 2.0f * ai[i] - a2[i]);
        o.z = 0.25f * (a0[i] - 2.0f * ar[i] + a2[i]);
        o.w = 0.25f * (a0[i] + 2.0f * ai[i] - a2[i]);
        *(float4*)(row + 16 * t + 4 * i) = o;
    }
}

// ============================== launch =====================================

extern "C" void kernel_launch(void* const* d_in, const int* in_sizes, int n_in,
                              void* d_out, int out_size, void* d_ws, size_t ws_size,
                              hipStream_t stream) {
    const float* x   = (const float*)d_in[0];
    const float* eig = (const float*)d_in[1];
    float* out = (float*)d_out;

    const size_t NEED = (size_t)50 * 1024 * 1024;

    if (ws_size >= NEED) {
        unsigned short* Xp = (unsigned short*)d_ws;                      // 40 MiB
        unsigned short* Bp = (unsigned short*)((char*)d_ws + 41943040u); // 10 MiB

        pre_k<<<5120, 256, 0, stream>>>(x, eig, Xp, Bp);
        gemm_f<<<256, 512, 0, stream>>>(Xp, Bp, out);
    } else {
        unsigned short* Xp = (unsigned short*)d_ws;
        unsigned short* Bp = Xp + (size_t)NDIM * NDIM;

        fwd_x_fb<<<(NDIM * 1024) / 256, 256, 0, stream>>>(x, Xp);
        build_b_fb<<<(1024 * 1024) / 256, 256, 0, stream>>>(eig, Bp);
        gemm_fb<<<dim3(1024, 1), 256, 0, stream>>>(Xp, Bp, out);
        post_fb<<<NDIM, 256, 0, stream>>>(out);
    }
}

// Round 2
// 184.033 us; speedup vs baseline: 1.1601x; 1.0232x over previous
//
#include <hip/hip_runtime.h>

// ---------------------------------------------------------------------------
// CirculantLinear, fully fused GEMM path, round 3.
//
// Karatsuba in frequency space: K1=(Xr+Xi)Er, K2=Xr(Ei-Er), K3=Xi(Ei+Er)
//   Or = K1-K3, Oi = K1+K2
// ONE flat K=5120 bf16 GEMM per output tile:
//   A  = Xp 4096 x 5120 = [Xs | Xr | Xi | X0 | X2]
//   B  = Bp 1024 x 5120 = [Er | Ei-Er | -(Ei+Er) | E0 | E2]   (row = y)
// Accumulator target switches every 1024 k; irfft4 in the epilogue.
//
// Round-3 change (T4 counted vmcnt): 3-buffer LDS rotation (96 KB), loads
// pipelined 2 K-steps deep, RAW s_barrier (no implicit vmcnt(0) drain like
// __syncthreads) + hand-placed s_waitcnt vmcnt(4) — tile t's loads waited
// while tile t+1's 4 loads stay in flight across the barrier. Never drains
// to 0 in the main loop (m218 lever). setprio(1) around MFMA (T5).
//
// ws: [0,40MiB) Xp bf16 4096x5120 ; [40,50MiB) Bp bf16 1024x5120
// ---------------------------------------------------------------------------

typedef __attribute__((ext_vector_type(8))) short bf16x8_t;
typedef __attribute__((ext_vector_type(4))) float f32x4_t;

#define NDIM 4096
#define TILE 128
#define BK 32

__device__ __forceinline__ unsigned short f2bf(float f) {
    unsigned int u = __builtin_bit_cast(unsigned int, f);
    u += 0x7fffu + ((u >> 16) & 1u);
    return (unsigned short)(u >> 16);
}

__device__ __forceinline__ void async_copy16(const void* g, void* l) {
    __builtin_amdgcn_global_load_lds(
        (const __attribute__((address_space(1))) void*)g,
        (__attribute__((address_space(3))) void*)l,
        16, 0, 0);
}

// ======================= PRIMARY (fused) path ==============================

// pre-pass: 4 mini-blocks per thread, 8-byte stores per panel.
__global__ __launch_bounds__(256) void pre_k(const float* __restrict__ x,
                                             const float* __restrict__ eig,
                                             unsigned short* __restrict__ xp,
                                             unsigned short* __restrict__ B) {
    const int t = threadIdx.x;
    if (blockIdx.x < 4096) {
        int gid = blockIdx.x * 256 + t;
        int b = gid >> 8, j0 = (gid & 255) << 2;
        const float4* src = (const float4*)x + ((size_t)b << 10) + j0;
        unsigned short S[4], R[4], Mi[4], Z[4], T[4];
#pragma unroll
        for (int q = 0; q < 4; ++q) {
            float4 v = src[q];
            float r = v.x - v.z, m = v.w - v.y;
            S[q]  = f2bf(r + m);                     // Xs = Xr+Xi
            R[q]  = f2bf(r);                         // Xr
            Mi[q] = f2bf(m);                         // Xi
            Z[q]  = f2bf(v.x + v.y + v.z + v.w);     // X0
            T[q]  = f2bf(v.x - v.y + v.z - v.w);     // X2
        }
        unsigned short* dst = xp + (size_t)b * 5120 + j0;
        *(ushort4*)(dst)        = *(const ushort4*)S;
        *(ushort4*)(dst + 1024) = *(const ushort4*)R;
        *(ushort4*)(dst + 2048) = *(const ushort4*)Mi;
        *(ushort4*)(dst + 3072) = *(const ushort4*)Z;
        *(ushort4*)(dst + 4096) = *(const ushort4*)T;
    } else {
        int gid = (blockIdx.x - 4096) * 256 + t;
        int y = gid >> 8, c0 = (gid & 255) << 2;
        const float4* src = (const float4*)eig + ((size_t)y << 10) + c0;
        unsigned short P0[4], P1[4], P2[4], P3[4], P4[4];
#pragma unroll
        for (int q = 0; q < 4; ++q) {
            float4 v = src[q];
            float r = v.x - v.z, m = v.w - v.y;      // Er, Ei
            P0[q] = f2bf(r);                         // Er
            P1[q] = f2bf(m - r);                     // Ei-Er
            P2[q] = f2bf(-(m + r));                  // -(Ei+Er)
            P3[q] = f2bf(v.x + v.y + v.z + v.w);     // E0
            P4[q] = f2bf(v.x - v.y + v.z - v.w);     // E2
        }
        unsigned short* dst = B + (size_t)y * 5120 + c0;
        *(ushort4*)(dst)        = *(const ushort4*)P0;
        *(ushort4*)(dst + 1024) = *(const ushort4*)P1;
        *(ushort4*)(dst + 2048) = *(const ushort4*)P2;
        *(ushort4*)(dst + 3072) = *(const ushort4*)P3;
        *(ushort4*)(dst + 4096) = *(const ushort4*)P4;
    }
}

// Fused GEMM + irfft epilogue. Grid: 256 blocks = 32 rowBlks x 8 colBlks.
__global__ __launch_bounds__(512, 2) void gemm_f(
        const unsigned short* __restrict__ A,   // Xp 4096 x 5120
        const unsigned short* __restrict__ B,   // Bp 1024 x 5120
        float* __restrict__ C) {                // out 4096 x 4096
    // 3 rotating buffers x [ A tile 128x64 (16KB) | B tile 128x64 (16KB) ]
    __shared__ unsigned short sm[3][16384];

    const int raw    = blockIdx.x;
    const int xcd    = raw & 7;
    const int idx    = raw >> 3;                 // [0,32)
    const int rowBlk = xcd * 4 + (idx >> 3);     // [0,32)
    const int colBlk = idx & 7;                  // [0,8)

    const int t    = threadIdx.x;
    const int lane = t & 63;
    const int w    = t >> 6;                     // [0,8)
    const int wm   = (w >> 2) * 64;              // 2 M-waves
    const int wn   = (w & 3) * 32;               // 4 N-waves
    const int lr   = lane & 15;
    const int quad = lane >> 4;
    const int xr   = lr & 7;                     // read-side XOR swizzle key

    // staging: thread t loads 16B for LDS slot (row=t>>3, col8=t&7); the
    // GLOBAL source is pre-swizzled (col8L = col8 ^ (row&7)) so swizzled
    // reads below see logical data (both-sides-or-neither rule).
    const int srow = t >> 3;                                   // [0,64)
    const int scol = ((t & 7) ^ ((t >> 3) & 7)) << 3;          // u16 in BK=64 window
    const unsigned short* pa0 = A + (size_t)(rowBlk * 128 + srow) * 5120 + scol;
    const unsigned short* pa1 = pa0 + (size_t)64 * 5120;
    const unsigned short* pb0 = B + (size_t)(colBlk * 128 + srow) * 5120 + scol;
    const unsigned short* pb1 = pb0 + (size_t)64 * 5120;

    char* smb  = (char*)&sm[0][0];
    char* dstT = smb + (size_t)t * 16;

    int koff = 0;   // next k (u16) to prefetch

    f32x4_t aK1[4][2] = {};   // K1, becomes Or
    f32x4_t aOi[4][2];        // Oi = K1 + K2 (init by copy)
    f32x4_t aO0[4][2] = {};
    f32x4_t aO2[4][2] = {};

#define STAGE_F(BOFF)                                          \
    {                                                          \
        char* d = dstT + (BOFF);                               \
        async_copy16(pa0 + koff, d);                           \
        async_copy16(pa1 + koff, d + 8192);                    \
        async_copy16(pb0 + koff, d + 16384);                   \
        async_copy16(pb1 + koff, d + 24576);                   \
        koff += 64;                                            \
    }

#define COMPUTE_F(BOFF, ACC)                                                  \
    {                                                                         \
        const char* ab = smb + (BOFF) + (wm + lr) * 128;                      \
        const char* bb = smb + (BOFF) + 16384 + (wn + lr) * 128;              \
        _Pragma("unroll")                                                     \
        for (int kk = 0; kk < 2; ++kk) {                                      \
            const int sw = ((((kk << 2) | quad)) ^ xr) << 4;                  \
            bf16x8_t af[4], bfv[2];                                           \
            _Pragma("unroll")                                                 \
            for (int i = 0; i < 4; ++i)                                       \
                af[i] = *(const bf16x8_t*)(ab + i * 2048 + sw);               \
            _Pragma("unroll")                                                 \
            for (int j = 0; j < 2; ++j)                                       \
                bfv[j] = *(const bf16x8_t*)(bb + j * 2048 + sw);              \
            __builtin_amdgcn_s_setprio(1);                                    \
            _Pragma("unroll")                                                 \
            for (int mt = 0; mt < 4; ++mt)                                    \
                _Pragma("unroll")                                             \
                for (int nt = 0; nt < 2; ++nt)                                \
                    ACC[mt][nt] = __builtin_amdgcn_mfma_f32_16x16x32_bf16(    \
                        af[mt], bfv[nt], ACC[mt][nt], 0, 0, 0);               \
            __builtin_amdgcn_s_setprio(0);                                    \
        }                                                                     \
    }

    // One step: wait tile t (leaving tile t+1's 4 loads in flight), raw
    // barrier (NO implicit vmcnt(0) drain), stage tile t+2 into the buffer
    // computed at t-1 (safe: all waves crossed this barrier after computing
    // t-1), then compute tile t. Single barrier per K-step.
#define STEP_F(ACC)                                            \
    {                                                          \
        asm volatile("s_waitcnt vmcnt(4)" ::: "memory");       \
        __builtin_amdgcn_s_barrier();                          \
        __builtin_amdgcn_sched_barrier(0);                     \
        int sb_ = cb + 65536;                                  \
        if (sb_ >= 98304) sb_ -= 98304;                        \
        if (koff < 5120) STAGE_F(sb_);                         \
        COMPUTE_F(cb, ACC);                                    \
        cb += 32768;                                           \
        if (cb >= 98304) cb = 0;                               \
    }

#define PHASE_F(ACC, NSTEP)                                    \
    _Pragma("unroll 1")                                        \
    for (int s2 = 0; s2 < (NSTEP); ++s2) STEP_F(ACC)

    // prologue: tiles 0,1 into buffers 0,1 -> 8 loads/thread in flight
    STAGE_F(0);
    STAGE_F(32768);
    int cb = 0;

    PHASE_F(aK1, 16)                // k [   0,1024): K1 = Xs*Er
#pragma unroll
    for (int mt = 0; mt < 4; ++mt)
#pragma unroll
        for (int nt = 0; nt < 2; ++nt) aOi[mt][nt] = aK1[mt][nt];
    PHASE_F(aOi, 16)                // k [1024,2048): += K2  -> Oi
    PHASE_F(aK1, 16)                // k [2048,3072): += -K3 -> Or
    PHASE_F(aO0, 16)                // k [3072,4096): O0
    PHASE_F(aO2, 15)                // k [4096,5088): O2 (first 15 steps)

    // tail step 79: only tile 79's 4 loads outstanding -> drain fully
    asm volatile("s_waitcnt vmcnt(0)" ::: "memory");
    __builtin_amdgcn_s_barrier();
    __builtin_amdgcn_sched_barrier(0);
    COMPUTE_F(cb, aO2);

#undef PHASE_F
#undef STEP_F
#undef COMPUTE_F
#undef STAGE_F

    // epilogue: irfft4 in registers, final-output float4 stores only.
    const int orow0 = rowBlk * 128 + wm + quad * 4;
    const int yc0   = colBlk * 128 + wn + lr;
#pragma unroll
    for (int mt = 0; mt < 4; ++mt) {
#pragma unroll
        for (int r = 0; r < 4; ++r) {
            float* dst = C + (size_t)(orow0 + mt * 16 + r) * NDIM;
#pragma unroll
            for (int nt = 0; nt < 2; ++nt) {
                int yc = yc0 + nt * 16;
                float O0 = aO0[mt][nt][r], Or = aK1[mt][nt][r];
                float Oi = aOi[mt][nt][r], O2 = aO2[mt][nt][r];
                float4 o;
                o.x = 0.25f * (O0 + 2.0f * Or + O2);
                o.y = 0.25f * (O0 - 2.0f * Oi - O2);
                o.z = 0.25f * (O0 - 2.0f * Or + O2);
                o.w = 0.25f * (O0 + 2.0f * Oi - O2);
                *(float4*)(dst + 4 * yc) = o;
            }
        }
    }
}

// ======================= FALLBACK (round-2 path) ===========================

__global__ __launch_bounds__(256) void fwd_x_fb(const float* __restrict__ x,
                                                unsigned short* __restrict__ xp) {
    int gid = blockIdx.x * 256 + threadIdx.x;
    int b = gid >> 10, j = gid & 1023;
    float4 v = ((const float4*)x)[(size_t)b * 1024 + j];
    unsigned short* dst = xp + (size_t)b * NDIM + j;
    dst[0]    = f2bf(v.x + v.y + v.z + v.w);
    dst[1024] = f2bf(v.x - v.z);
    dst[2048] = f2bf(v.w - v.y);
    dst[3072] = f2bf(v.x - v.y + v.z - v.w);
}

__global__ __launch_bounds__(256) void build_b_fb(const float* __restrict__ eig,
                                                  unsigned short* __restrict__ B) {
    int gid = blockIdx.x * 256 + threadIdx.x;
    int y = gid >> 10, c = gid & 1023;
    float4 v = ((const float4*)eig)[(size_t)y * 1024 + c];
    float r = v.x - v.z, s = v.w - v.y;
    B[(size_t)y * 1024 + c] = f2bf(v.x + v.y + v.z + v.w);
    unsigned short* b1r = B + 1048576 + (size_t)y * 2048;
    b1r[c]        = f2bf(r);
    b1r[1024 + c] = f2bf(-s);
    unsigned short* b1i = B + 3145728 + (size_t)y * 2048;
    b1i[c]        = f2bf(s);
    b1i[1024 + c] = f2bf(r);
    B[5242880 + (size_t)y * 1024 + c] = f2bf(v.x - v.y + v.z - v.w);
}

__global__ __launch_bounds__(256, 2) void gemm_fb(
        const unsigned short* __restrict__ A,
        const unsigned short* __restrict__ B,
        float* __restrict__ C) {
    __shared__ unsigned short lA[TILE * BK];
    __shared__ unsigned short lB[TILE * BK];

    const int Ks[4]   = {1024, 2048, 2048, 1024};
    const int Aoff[4] = {0, 1024, 1024, 3072};
    const size_t Boff[4] = {0u, 1048576u, 3145728u, 5242880u};

    int lin = blockIdx.x;
    int seg, nseg, blkM;
    if (lin < 512) { seg = 1 + ((lin >> 3) & 1); nseg = lin & 7; blkM = lin >> 4; }
    else { int i = lin - 512; seg = ((i >> 3) & 1) * 3; nseg = i & 7; blkM = i >> 4; }

    const int K    = Ks[seg];
    const int aoff = Aoff[seg];
    const unsigned short* Bs = B + Boff[seg];

    const int t    = threadIdx.x;
    const int lane = t & 63;
    const int w    = t >> 6;
    const int wm   = (w >> 1) * 64;
    const int wn   = (w & 1) * 64;
    const int lr   = lane & 15;
    const int quad = lane >> 4;

    const int e0 = t * 8;
    const int r0 = e0 >> 5;
    const int c0 = e0 & 31;

    const unsigned short* pa0 = A + (size_t)(blkM * TILE + r0) * NDIM + aoff + c0;
    const unsigned short* pa1 = pa0 + (size_t)64 * NDIM;
    const unsigned short* pb0 = Bs + (size_t)(nseg * TILE + r0) * K + c0;
    const unsigned short* pb1 = pb0 + (size_t)64 * K;

    unsigned short* dA0 = &lA[e0];
    unsigned short* dA1 = &lA[2048 + e0];
    unsigned short* dB0 = &lB[e0];
    unsigned short* dB1 = &lB[2048 + e0];

    const unsigned short* la0 = &lA[(wm + lr) * BK + quad * 8];
    const unsigned short* lb0 = &lB[(wn + lr) * BK + quad * 8];

    f32x4_t acc[4][4] = {};

    for (int k0 = 0; k0 < K; k0 += BK) {
        async_copy16(pa0 + k0, dA0);
        async_copy16(pa1 + k0, dA1);
        async_copy16(pb0 + k0, dB0);
        async_copy16(pb1 + k0, dB1);
        asm volatile("s_waitcnt vmcnt(0)" ::: "memory");
        __syncthreads();

        bf16x8_t af[4], bfr[4];
#pragma unroll
        for (int i = 0; i < 4; ++i)
            af[i] = *(const bf16x8_t*)(la0 + i * 16 * BK);
#pragma unroll
        for (int i = 0; i < 4; ++i)
            bfr[i] = *(const bf16x8_t*)(lb0 + i * 16 * BK);

#pragma unroll
        for (int mt = 0; mt < 4; ++mt)
#pragma unroll
            for (int nt = 0; nt < 4; ++nt)
                acc[mt][nt] = __builtin_amdgcn_mfma_f32_16x16x32_bf16(
                    af[mt], bfr[nt], acc[mt][nt], 0, 0, 0);

        __syncthreads();
    }

    const int orow0 = blkM * TILE + wm + quad * 4;
    const int ocol0 = seg * 1024 + nseg * TILE + wn + lr;
#pragma unroll
    for (int mt = 0; mt < 4; ++mt) {
#pragma unroll
        for (int r = 0; r < 4; ++r) {
            float* dst = C + (size_t)(orow0 + mt * 16 + r) * NDIM + ocol0;
#pragma unroll
            for (int nt = 0; nt < 4; ++nt)
                dst[nt * 16] = acc[mt][nt][r];
        }
    }
}

__global__ __launch_bounds__(256) void post_fb(float* __restrict__ O) {
    float* row = O + (size_t)blockIdx.x * NDIM;
    const int t = threadIdx.x;
    float4 v0 = *(const float4*)(row + 4 * t);
    float4 vr = *(const float4*)(row + 1024 + 4 * t);
    float4 vi = *(const float4*)(row + 2048 + 4 * t);
    float4 v2 = *(const float4*)(row + 3072 + 4 * t);
    __syncthreads();
    const float* a0 = (const float*)&v0;
    const float* ar = (const float*)&vr;
    const float* ai = (const float*)&vi;
    const float* a2 = (const float*)&v2;
#pragma unroll
    for (int i = 0; i < 4; ++i) {
        float4 o;
        o.x = 0.25f * (a0[i] + 2.0f * ar[i] + a2[i]);
        o.y = 0.25f * (a0[i] - 2.0f * ai[i] - a2[i]);
        o.z = 0.25f * (a0[i] - 2.0f * ar[i] + a2[i]);
        o.w = 0.25f * (a0[i] + 2.0f * ai[i] - a2[i]);
        *(float4*)(row + 16 * t + 4 * i) = o;
    }
}

// ============================== launch =====================================

extern "C" void kernel_launch(void* const* d_in, const int* in_sizes, int n_in,
                              void* d_out, int out_size, void* d_ws, size_t ws_size,
                              hipStream_t stream) {
    const float* x   = (const float*)d_in[0];
    const float* eig = (const float*)d_in[1];
    float* out = (float*)d_out;

    const size_t NEED = (size_t)50 * 1024 * 1024;

    if (ws_size >= NEED) {
        unsigned short* Xp = (unsigned short*)d_ws;                      // 40 MiB
        unsigned short* Bp = (unsigned short*)((char*)d_ws + 41943040u); // 10 MiB

        pre_k<<<5120, 256, 0, stream>>>(x, eig, Xp, Bp);
        gemm_f<<<256, 512, 0, stream>>>(Xp, Bp, out);
    } else {
        unsigned short* Xp = (unsigned short*)d_ws;
        unsigned short* Bp = Xp + (size_t)NDIM * NDIM;

        fwd_x_fb<<<(NDIM * 1024) / 256, 256, 0, stream>>>(x, Xp);
        build_b_fb<<<(1024 * 1024) / 256, 256, 0, stream>>>(eig, Bp);
        gemm_fb<<<dim3(1024, 1), 256, 0, stream>>>(Xp, Bp, out);
        post_fb<<<NDIM, 256, 0, stream>>>(out);
    }
}